// Round 1
// baseline (3127.613 us; speedup 1.0000x reference)
//
#include <hip/hip_runtime.h>

#define HIDDEN 128
#define NRAD 6

// P1[a][h] = b_lin[h] + sum_k emb[a][k] * w_lin[h][k]        (k in [0,128))
// P2[a][h] =            sum_k emb[a][k] * w_lin[h][128+k]
__global__ void precompute_kernel(const float* __restrict__ emb,
                                  const float* __restrict__ w_lin,
                                  const float* __restrict__ b_lin,
                                  float* __restrict__ P1,
                                  float* __restrict__ P2) {
    __shared__ __align__(16) float erow[HIDDEN];
    const int a = blockIdx.x;
    const int h = threadIdx.x;
    erow[h] = emb[a * HIDDEN + h];
    __syncthreads();
    float acc1 = b_lin[h];
    float acc2 = 0.f;
    const float* __restrict__ w1 = w_lin + h * 384;
    const float* __restrict__ w2 = w1 + HIDDEN;
#pragma unroll 8
    for (int k = 0; k < HIDDEN; ++k) {
        acc1 += erow[k] * w1[k];
        acc2 += erow[k] * w2[k];
    }
    P1[a * HIDDEN + h] = acc1;
    P2[a * HIDDEN + h] = acc2;
}

__device__ __forceinline__ float swishf(float v) {
    return v / (1.0f + __expf(-v));
}

__global__ __launch_bounds__(128, 2)
void edge_kernel(const int* __restrict__ xv,
                 const float* __restrict__ rbf,
                 const int* __restrict__ iv,
                 const int* __restrict__ jv,
                 const float* __restrict__ w_rbf0,
                 const float* __restrict__ b_rbf0,
                 const float* __restrict__ w_rbf1,
                 const float* __restrict__ w_lin,
                 const float* __restrict__ P1,
                 const float* __restrict__ P2,
                 float* __restrict__ out_e1,
                 float* __restrict__ out_e2,
                 int n_edges, int pairs_per_block) {
    __shared__ __align__(16) float r0a[HIDDEN];
    __shared__ __align__(16) float r0b[HIDDEN];
    const int h = threadIdx.x;

    // Register-resident W3 row: w_lin[h][256 + k], k = 0..127
    float wrow[HIDDEN];
    {
        const float4* __restrict__ src =
            reinterpret_cast<const float4*>(w_lin + h * 384 + 256);
#pragma unroll
        for (int q = 0; q < HIDDEN / 4; ++q) {
            float4 v = src[q];
            wrow[4 * q + 0] = v.x;
            wrow[4 * q + 1] = v.y;
            wrow[4 * q + 2] = v.z;
            wrow[4 * q + 3] = v.w;
        }
    }
    float wr0[NRAD], wr1[NRAD];
#pragma unroll
    for (int r = 0; r < NRAD; ++r) {
        wr0[r] = w_rbf0[h * NRAD + r];
        wr1[r] = w_rbf1[h * NRAD + r];
    }
    const float b0 = b_rbf0[h];

    const int total_pairs = (n_edges + 1) >> 1;
    const int pair_start = blockIdx.x * pairs_per_block;
    const int pair_end = min(pair_start + pairs_per_block, total_pairs);

    for (int p = pair_start; p < pair_end; ++p) {
        const int e0 = 2 * p;
        const int e1i = e0 + 1;
        const bool has_b = (e1i < n_edges);

        // Uniform (per-block) index chain -> compiler scalarizes.
        const int ia = iv[e0], ja = jv[e0];
        const int ib = has_b ? iv[e1i] : ia;
        const int jb = has_b ? jv[e1i] : ja;
        const int xai = xv[ia], xaj = xv[ja];
        const int xbi = xv[ib], xbj = xv[jb];

        float rva[NRAD], rvb[NRAD];
#pragma unroll
        for (int r = 0; r < NRAD; ++r) {
            rva[r] = rbf[(size_t)e0 * NRAD + r];
            rvb[r] = has_b ? rbf[(size_t)e1i * NRAD + r] : 0.f;
        }

        // Issue P gathers early (L2-resident 48 KB tables).
        const float p1a = P1[xai * HIDDEN + h];
        const float p2a = P2[xaj * HIDDEN + h];
        const float p1b = P1[xbi * HIDDEN + h];
        const float p2b = P2[xbj * HIDDEN + h];

        // rbf0 = swish(rbf @ w_rbf0^T + b_rbf0), one channel per thread.
        float va = b0, vb = b0;
#pragma unroll
        for (int r = 0; r < NRAD; ++r) {
            va += rva[r] * wr0[r];
            vb += rvb[r] * wr0[r];
        }
        va = swishf(va);
        vb = swishf(vb);

        __syncthreads();   // previous iteration's LDS reads complete
        r0a[h] = va;
        r0b[h] = vb;
        __syncthreads();   // rbf0 visible to all

        // 128x128 matvec: acc = sum_k rbf0[k] * W3[h][k]
        float aa0 = 0.f, aa1 = 0.f, aa2 = 0.f, aa3 = 0.f;
        float ab0 = 0.f, ab1 = 0.f, ab2 = 0.f, ab3 = 0.f;
        const float4* __restrict__ ra4 = reinterpret_cast<const float4*>(r0a);
        const float4* __restrict__ rb4 = reinterpret_cast<const float4*>(r0b);
#pragma unroll
        for (int q = 0; q < HIDDEN / 4; ++q) {
            const float4 fa = ra4[q];   // LDS broadcast (conflict-free)
            const float4 fb = rb4[q];
            aa0 += fa.x * wrow[4 * q + 0];
            aa1 += fa.y * wrow[4 * q + 1];
            aa2 += fa.z * wrow[4 * q + 2];
            aa3 += fa.w * wrow[4 * q + 3];
            ab0 += fb.x * wrow[4 * q + 0];
            ab1 += fb.y * wrow[4 * q + 1];
            ab2 += fb.z * wrow[4 * q + 2];
            ab3 += fb.w * wrow[4 * q + 3];
        }
        const float sa = (aa0 + aa1) + (aa2 + aa3) + p1a + p2a;
        const float sb = (ab0 + ab1) + (ab2 + ab3) + p1b + p2b;
        const float e1a = swishf(sa);
        const float e1b = swishf(sb);

        float qa = 0.f, qb = 0.f;
#pragma unroll
        for (int r = 0; r < NRAD; ++r) {
            qa += rva[r] * wr1[r];
            qb += rvb[r] * wr1[r];
        }

        out_e1[(size_t)e0 * HIDDEN + h] = e1a;
        out_e2[(size_t)e0 * HIDDEN + h] = qa * e1a;
        if (has_b) {
            out_e1[(size_t)e1i * HIDDEN + h] = e1b;
            out_e2[(size_t)e1i * HIDDEN + h] = qb * e1b;
        }
    }
}

extern "C" void kernel_launch(void* const* d_in, const int* in_sizes, int n_in,
                              void* d_out, int out_size, void* d_ws, size_t ws_size,
                              hipStream_t stream) {
    const int*   xv     = (const int*)  d_in[0];
    const float* rbf    = (const float*)d_in[1];
    const int*   iv     = (const int*)  d_in[2];
    const int*   jv     = (const int*)  d_in[3];
    const float* emb    = (const float*)d_in[4];
    const float* w_rbf0 = (const float*)d_in[5];
    const float* b_rbf0 = (const float*)d_in[6];
    const float* w_lin  = (const float*)d_in[7];
    const float* b_lin  = (const float*)d_in[8];
    const float* w_rbf1 = (const float*)d_in[9];

    const int n_edges = in_sizes[2];
    const int n_emb_rows = in_sizes[4] / HIDDEN;   // 95

    float* P1 = (float*)d_ws;
    float* P2 = P1 + (size_t)n_emb_rows * HIDDEN;

    float* out_e1 = (float*)d_out;
    float* out_e2 = out_e1 + (size_t)n_edges * HIDDEN;

    precompute_kernel<<<n_emb_rows, HIDDEN, 0, stream>>>(emb, w_lin, b_lin, P1, P2);

    const int total_pairs = (n_edges + 1) / 2;
    const int grid = 2048;
    const int ppb = (total_pairs + grid - 1) / grid;
    edge_kernel<<<grid, HIDDEN, 0, stream>>>(xv, rbf, iv, jv,
                                             w_rbf0, b_rbf0, w_rbf1, w_lin,
                                             P1, P2, out_e1, out_e2,
                                             n_edges, ppb);
}

// Round 3
// 886.503 us; speedup vs baseline: 3.5280x; 3.5280x over previous
//
#include <hip/hip_runtime.h>

#define HIDDEN 128
#define NRAD 6
#define W3LD 136   // padded W3 row stride in shorts (272 B) -> benign 2-way LDS aliasing

typedef short bf16x8 __attribute__((ext_vector_type(8)));
typedef float f32x4 __attribute__((ext_vector_type(4)));

__device__ __forceinline__ float fast_rcp(float x) {
    return __builtin_amdgcn_rcpf(x);
}

__device__ __forceinline__ float swishf(float v) {
    return v * fast_rcp(1.0f + __expf(-v));
}

// float -> bf16 (round-to-nearest-even)
__device__ __forceinline__ short f2bf(float f) {
    union { float f; unsigned u; } c; c.f = f;
    unsigned r = (c.u + 0x7FFFu + ((c.u >> 16) & 1u)) >> 16;
    return (short)(unsigned short)r;
}

// P1[a][h] = b_lin[h] + sum_k emb[a][k] * w_lin[h][k]        (k in [0,128))
// P2[a][h] =            sum_k emb[a][k] * w_lin[h][128+k]
__global__ void precompute_kernel(const float* __restrict__ emb,
                                  const float* __restrict__ w_lin,
                                  const float* __restrict__ b_lin,
                                  float* __restrict__ P1,
                                  float* __restrict__ P2) {
    __shared__ __align__(16) float erow[HIDDEN];
    const int a = blockIdx.x;
    const int h = threadIdx.x;
    erow[h] = emb[a * HIDDEN + h];
    __syncthreads();
    float acc1 = b_lin[h];
    float acc2 = 0.f;
    const float* __restrict__ w1 = w_lin + h * 384;
    const float* __restrict__ w2 = w1 + HIDDEN;
#pragma unroll 8
    for (int k = 0; k < HIDDEN; ++k) {
        acc1 += erow[k] * w1[k];
        acc2 += erow[k] * w2[k];
    }
    P1[a * HIDDEN + h] = acc1;
    P2[a * HIDDEN + h] = acc2;
}

struct MD {
    float2 ra, rb, rc;   // rbf[e][0..5]
    int xi, xj;          // xv[iv[e]], xv[jv[e]]
};

__device__ __forceinline__ MD load_md(int tile, int l15, int n_edges,
                                      const int* __restrict__ iv,
                                      const int* __restrict__ jv,
                                      const int* __restrict__ xv,
                                      const float* __restrict__ rbf) {
    int e = tile * 16 + l15;
    int ecl = (e < n_edges) ? e : (n_edges - 1);
    MD m;
    const float2* rp = reinterpret_cast<const float2*>(rbf + (size_t)ecl * NRAD);
    m.ra = rp[0];
    m.rb = rp[1];
    m.rc = rp[2];
    m.xi = xv[iv[ecl]];
    m.xj = xv[jv[ecl]];
    return m;
}

// Per wave: 16 edges x 128 channels via 8 n-tiles x 4 k-steps of
// mfma_f32_16x16x32_bf16.  A = rbf0 built in-register from the lane's own
// edge metadata; B = W3^T from padded LDS.  C/D: col=lane&15 (h-low),
// row=(lane>>4)*4+reg (edge).  A: lane holds A[lane&15][(lane>>4)*8+j];
// B: lane holds B[(lane>>4)*8+j][lane&15].
__global__ __launch_bounds__(256, 3)
void edge_mfma_kernel(const int* __restrict__ xv,
                      const float* __restrict__ rbf,
                      const int* __restrict__ iv,
                      const int* __restrict__ jv,
                      const float* __restrict__ w_rbf0,
                      const float* __restrict__ b_rbf0,
                      const float* __restrict__ w_rbf1,
                      const float* __restrict__ w_lin,
                      const float* __restrict__ P1,
                      const float* __restrict__ P2,
                      float* __restrict__ out_e1,
                      float* __restrict__ out_e2,
                      int n_edges, int tiles_per_block, int n_tiles) {
    __shared__ __align__(16) short w3s[HIDDEN * W3LD];
    __shared__ float w0s[HIDDEN * 9];    // stride 9: consecutive k -> distinct banks
    __shared__ float b0s[HIDDEN];

    const int tid = threadIdx.x;

    // ---- stage W3 = w_lin[h][256..383] as bf16 into padded rows ----
    {
        const int h = tid >> 1, kh = tid & 1;
        const float4* src =
            reinterpret_cast<const float4*>(w_lin + h * 384 + 256 + kh * 64);
#pragma unroll
        for (int s = 0; s < 8; ++s) {
            float4 va = src[2 * s];
            float4 vb = src[2 * s + 1];
            bf16x8 fr;
            fr[0] = f2bf(va.x); fr[1] = f2bf(va.y);
            fr[2] = f2bf(va.z); fr[3] = f2bf(va.w);
            fr[4] = f2bf(vb.x); fr[5] = f2bf(vb.y);
            fr[6] = f2bf(vb.z); fr[7] = f2bf(vb.w);
            const int slot = kh * 8 + s;
            *reinterpret_cast<bf16x8*>(&w3s[h * W3LD + slot * 8]) = fr;
        }
    }
    if (tid < HIDDEN) {
#pragma unroll
        for (int r = 0; r < NRAD; ++r)
            w0s[tid * 9 + r] = w_rbf0[tid * NRAD + r];
        b0s[tid] = b_rbf0[tid];
    }
    __syncthreads();

    const int wid = tid >> 6;
    const int lane = tid & 63;
    const int l15 = lane & 15;
    const int lg = lane >> 4;

    // per-lane w1 rows for epilogue: h = nt*16 + l15 (tiny, L1/L2 resident)
    float w1r[8][NRAD];
#pragma unroll
    for (int nt = 0; nt < 8; ++nt)
#pragma unroll
        for (int r = 0; r < NRAD; ++r)
            w1r[nt][r] = w_rbf1[(nt * 16 + l15) * NRAD + r];

    const int bt = blockIdx.x * tiles_per_block;
    const int btEnd = min(bt + tiles_per_block, n_tiles);

    int t = bt + wid;
    MD cur = load_md(t, l15, n_edges, iv, jv, xv, rbf);

    for (; t < btEnd; t += 4) {
        MD nxt = load_md(t + 4, l15, n_edges, iv, jv, xv, rbf);  // hide latency

        f32x4 acc[8];
#pragma unroll
        for (int nt = 0; nt < 8; ++nt) acc[nt] = (f32x4){0.f, 0.f, 0.f, 0.f};

#pragma unroll
        for (int ks = 0; ks < 4; ++ks) {
            // A fragment: rbf0[e = l15][k = ks*32 + lg*8 + j], lane-local math
            bf16x8 a;
#pragma unroll
            for (int j = 0; j < 8; ++j) {
                const int k = ks * 32 + lg * 8 + j;
                float tv = b0s[k]
                         + cur.ra.x * w0s[k * 9 + 0] + cur.ra.y * w0s[k * 9 + 1]
                         + cur.rb.x * w0s[k * 9 + 2] + cur.rb.y * w0s[k * 9 + 3]
                         + cur.rc.x * w0s[k * 9 + 4] + cur.rc.y * w0s[k * 9 + 5];
                a[j] = f2bf(swishf(tv));
            }
#pragma unroll
            for (int nt = 0; nt < 8; ++nt) {
                const bf16x8 b = *reinterpret_cast<const bf16x8*>(
                    &w3s[(nt * 16 + l15) * W3LD + (ks * 4 + lg) * 8]);
                acc[nt] = __builtin_amdgcn_mfma_f32_16x16x32_bf16(a, b, acc[nt], 0, 0, 0);
            }
        }

        const int eb = t * 16;
#pragma unroll
        for (int q = 0; q < 4; ++q) {
            const int el = lg * 4 + q;          // edge row of acc[*][q]
            const int eg = eb + el;
            const int xi = __shfl(cur.xi, el);  // lane el owns row el's metadata
            const int xj = __shfl(cur.xj, el);
            const float q0 = __shfl(cur.ra.x, el), q1 = __shfl(cur.ra.y, el);
            const float q2 = __shfl(cur.rb.x, el), q3 = __shfl(cur.rb.y, el);
            const float q4 = __shfl(cur.rc.x, el), q5 = __shfl(cur.rc.y, el);

            const float* p1p = P1 + xi * HIDDEN + l15;
            const float* p2p = P2 + xj * HIDDEN + l15;
            float p1v[8], p2v[8];
#pragma unroll
            for (int nt = 0; nt < 8; ++nt) {
                p1v[nt] = p1p[nt * 16];
                p2v[nt] = p2p[nt * 16];
            }
            if (eg < n_edges) {
                float* o1 = out_e1 + (size_t)eg * HIDDEN + l15;
                float* o2 = out_e2 + (size_t)eg * HIDDEN + l15;
#pragma unroll
                for (int nt = 0; nt < 8; ++nt) {
                    const float s = acc[nt][q] + p1v[nt] + p2v[nt];
                    const float e1v = swishf(s);
                    const float qd = q0 * w1r[nt][0] + q1 * w1r[nt][1]
                                   + q2 * w1r[nt][2] + q3 * w1r[nt][3]
                                   + q4 * w1r[nt][4] + q5 * w1r[nt][5];
                    __builtin_nontemporal_store(e1v, o1 + nt * 16);
                    __builtin_nontemporal_store(qd * e1v, o2 + nt * 16);
                }
            }
        }
        cur = nxt;
    }
}

extern "C" void kernel_launch(void* const* d_in, const int* in_sizes, int n_in,
                              void* d_out, int out_size, void* d_ws, size_t ws_size,
                              hipStream_t stream) {
    const int*   xv     = (const int*)  d_in[0];
    const float* rbf    = (const float*)d_in[1];
    const int*   iv     = (const int*)  d_in[2];
    const int*   jv     = (const int*)  d_in[3];
    const float* emb    = (const float*)d_in[4];
    const float* w_rbf0 = (const float*)d_in[5];
    const float* b_rbf0 = (const float*)d_in[6];
    const float* w_lin  = (const float*)d_in[7];
    const float* b_lin  = (const float*)d_in[8];
    const float* w_rbf1 = (const float*)d_in[9];

    const int n_edges = in_sizes[2];
    const int n_emb_rows = in_sizes[4] / HIDDEN;   // 95

    float* P1 = (float*)d_ws;
    float* P2 = P1 + (size_t)n_emb_rows * HIDDEN;

    float* out_e1 = (float*)d_out;
    float* out_e2 = out_e1 + (size_t)n_edges * HIDDEN;

    precompute_kernel<<<n_emb_rows, HIDDEN, 0, stream>>>(emb, w_lin, b_lin, P1, P2);

    const int n_tiles = (n_edges + 15) / 16;
    const int grid = 768;
    const int tpb = (n_tiles + grid - 1) / grid;
    edge_mfma_kernel<<<grid, 256, 0, stream>>>(xv, rbf, iv, jv,
                                               w_rbf0, b_rbf0, w_rbf1, w_lin,
                                               P1, P2, out_e1, out_e2,
                                               n_edges, tpb, n_tiles);
}